// Round 1
// 387.806 us; speedup vs baseline: 1.0408x; 1.0408x over previous
//
#include <hip/hip_runtime.h>
#include <math.h>

// Problem: N=8192 nodes, D=256 features, H=64 hidden.
// out = [h_out (N*D floats), e (N floats)] concatenated, fp32.
// d_ws holds g[j,:] = bf16(e[j] * h[j,:])  (N*D bf16 = 4 MB) — fits per-XCD L2.

typedef float nfloat4 __attribute__((ext_vector_type(4)));

__device__ inline float bf16_to_f32(unsigned short s) {
    union { unsigned u; float f; } c; c.u = ((unsigned)s) << 16; return c.f;
}
__device__ inline unsigned short f32_to_bf16(float f) {   // RNE, finite inputs
    union { float f; unsigned u; } c; c.f = f;
    unsigned r = c.u + 0x7FFFu + ((c.u >> 16) & 1u);
    return (unsigned short)(r >> 16);
}
// broadcast lane l's value to all lanes (l is compile-time after unroll)
__device__ inline float rdlane(float v, int l) {
    return __builtin_bit_cast(float,
        __builtin_amdgcn_readlane(__builtin_bit_cast(int, v), l));
}

// ---------------- Kernel 1: gate + bf16 pre-scale ----------------------------
// e = sigmoid(relu(h@W1+b1)@W2+b2); g[i,:] = bf16(e[i]*h[i,:])
// Block = 256 threads (4 waves), stages W1 (64 KB) in LDS; wave handles 4 of
// the block's 16 rows; lane k owns hidden unit k / float4 feature slot k.
// v2: h row loaded ONCE coalesced (1 KB/wave) into hr, then broadcast with
// v_readlane (compile-time lane idx) — removes 64 latency-bound uniform
// global loads per row. FMA order identical to v1 (bit-identical output).
__global__ __launch_bounds__(256) void gate_kernel(const float* __restrict__ h,
                                                   const float* __restrict__ W1,
                                                   const float* __restrict__ b1,
                                                   const float* __restrict__ W2,
                                                   const float* __restrict__ b2,
                                                   float* __restrict__ e_out,
                                                   unsigned short* __restrict__ g_out,
                                                   int N) {
    __shared__ float W1s[256 * 64];            // 64 KB (2 blocks/CU)
    const int tid = threadIdx.x;

    const float4* W1v = reinterpret_cast<const float4*>(W1);
    float4* W1sv = reinterpret_cast<float4*>(W1s);
    #pragma unroll
    for (int t = 0; t < 16; ++t) W1sv[tid + 256 * t] = W1v[tid + 256 * t];
    __syncthreads();

    const int wave = tid >> 6;
    const int k    = tid & 63;
    const float b1k = b1[k];
    const float w2k = W2[k];
    const float b2v = b2[0];

    const int base = blockIdx.x * 16;
    for (int r = wave; r < 16; r += 4) {
        const int i = base + r;
        if (i >= N) break;
        const float4* hv = reinterpret_cast<const float4*>(h + (size_t)i * 256);
        float4 hr = hv[k];                     // one coalesced 1 KB row load
        float acc = 0.f;
        #pragma unroll
        for (int d4 = 0; d4 < 64; ++d4) {
            const int d = d4 * 4;
            // lane d4 holds h[i, 4*d4 .. 4*d4+3]
            float ax = rdlane(hr.x, d4);
            float ay = rdlane(hr.y, d4);
            float az = rdlane(hr.z, d4);
            float aw = rdlane(hr.w, d4);
            acc = fmaf(ax, W1s[(d + 0) * 64 + k], acc);
            acc = fmaf(ay, W1s[(d + 1) * 64 + k], acc);
            acc = fmaf(az, W1s[(d + 2) * 64 + k], acc);
            acc = fmaf(aw, W1s[(d + 3) * 64 + k], acc);
        }
        float v = fmaxf(acc + b1k, 0.f) * w2k;
        #pragma unroll
        for (int off = 32; off > 0; off >>= 1) v += __shfl_down(v, off);
        float vs = __shfl(v, 0);
        float ev = 1.f / (1.f + expf(-(vs + b2v)));
        if (k == 0) e_out[i] = ev;
        // g[i, 4k..4k+3] = bf16(ev * h[i, 4k..4k+3])  (8 B/lane store)
        ushort4 p;
        p.x = f32_to_bf16(ev * hr.x);
        p.y = f32_to_bf16(ev * hr.y);
        p.z = f32_to_bf16(ev * hr.z);
        p.w = f32_to_bf16(ev * hr.w);
        reinterpret_cast<ushort4*>(g_out + (size_t)i * 256)[k] = p;
    }
}

// ---------------- Kernel 2: h_out[i,:] = sum_{j: A[i,j]>0} g[j,:] ------------
// One wave per row; lane owns features 4*lane..4*lane+3 (fp32 float4 acc).
// A scanned with NON-TEMPORAL float4 loads (zero reuse, evict-first -> doesn't
// displace the 4 MB bf16 g from L2). v2: software-pipelined TWO groups ahead
// (2 KB/wave of A in flight) so the A-stream stays BW-saturated while the
// dependent ballot/ctz gather rounds resolve. Four ballot sub-masks processed
// in one interleaved loop (wave-uniform branches); each gather is a 512 B/wave
// bf16 row read, expected L2-resident.
__global__ __launch_bounds__(256) void agg_kernel(const float* __restrict__ A,
                                                  const unsigned short* __restrict__ g,
                                                  float* __restrict__ h_out,
                                                  int N) {
    const int tid  = threadIdx.x;
    const int lane = tid & 63;
    const int i    = blockIdx.x * 4 + (tid >> 6);   // row per wave
    if (i >= N) return;

    const nfloat4* Arow = reinterpret_cast<const nfloat4*>(A + (size_t)i * N);
    const ushort4* gv   = reinterpret_cast<const ushort4*>(g);  // g[j][4d..] = gv[j*64+d]

    float4 acc = {0.f, 0.f, 0.f, 0.f};
    const int groups = N / 256;                     // 32

    nfloat4 a0 = __builtin_nontemporal_load(&Arow[lane]);        // group 0
    nfloat4 a1 = __builtin_nontemporal_load(&Arow[64 + lane]);   // group 1
    nfloat4 a2 = {0.f, 0.f, 0.f, 0.f};

    for (int gi = 0; gi < groups; ++gi) {
        if (gi + 2 < groups)
            a2 = __builtin_nontemporal_load(&Arow[(gi + 2) * 64 + lane]);

        unsigned long long mx = __ballot(a0.x > 0.f);
        unsigned long long my = __ballot(a0.y > 0.f);
        unsigned long long mz = __ballot(a0.z > 0.f);
        unsigned long long mw = __ballot(a0.w > 0.f);
        const int jb = gi * 256;

        while (mx | my | mz | mw) {
            ushort4 ux, uy, uz, uw;
            bool px = mx != 0, py = my != 0, pz = mz != 0, pw = mw != 0;
            if (px) { int b = __builtin_ctzll(mx); mx &= mx - 1;
                      ux = gv[(size_t)(jb + 4 * b + 0) * 64 + lane]; }
            if (py) { int b = __builtin_ctzll(my); my &= my - 1;
                      uy = gv[(size_t)(jb + 4 * b + 1) * 64 + lane]; }
            if (pz) { int b = __builtin_ctzll(mz); mz &= mz - 1;
                      uz = gv[(size_t)(jb + 4 * b + 2) * 64 + lane]; }
            if (pw) { int b = __builtin_ctzll(mw); mw &= mw - 1;
                      uw = gv[(size_t)(jb + 4 * b + 3) * 64 + lane]; }
            if (px) { acc.x += bf16_to_f32(ux.x); acc.y += bf16_to_f32(ux.y);
                      acc.z += bf16_to_f32(ux.z); acc.w += bf16_to_f32(ux.w); }
            if (py) { acc.x += bf16_to_f32(uy.x); acc.y += bf16_to_f32(uy.y);
                      acc.z += bf16_to_f32(uy.z); acc.w += bf16_to_f32(uy.w); }
            if (pz) { acc.x += bf16_to_f32(uz.x); acc.y += bf16_to_f32(uz.y);
                      acc.z += bf16_to_f32(uz.z); acc.w += bf16_to_f32(uz.w); }
            if (pw) { acc.x += bf16_to_f32(uw.x); acc.y += bf16_to_f32(uw.y);
                      acc.z += bf16_to_f32(uw.z); acc.w += bf16_to_f32(uw.w); }
        }
        a0 = a1; a1 = a2;
    }

    // write-once output: non-temporal, keep L2 for g
    nfloat4 r; r.x = acc.x; r.y = acc.y; r.z = acc.z; r.w = acc.w;
    nfloat4* outv = reinterpret_cast<nfloat4*>(h_out + (size_t)i * 256);
    __builtin_nontemporal_store(r, &outv[lane]);
}

extern "C" void kernel_launch(void* const* d_in, const int* in_sizes, int n_in,
                              void* d_out, int out_size, void* d_ws, size_t ws_size,
                              hipStream_t stream) {
    const float* A  = (const float*)d_in[0];   // [N, N]
    const float* h  = (const float*)d_in[1];   // [N, D]
    const float* W1 = (const float*)d_in[2];   // [D, H]
    const float* b1 = (const float*)d_in[3];   // [H]
    const float* W2 = (const float*)d_in[4];   // [H, 1]
    const float* b2 = (const float*)d_in[5];   // [1]

    const int H = in_sizes[3];                 // 64
    const int D = in_sizes[2] / H;             // 256
    const int N = in_sizes[1] / D;             // 8192

    float* out   = (float*)d_out;
    float* h_out = out;                        // N*D
    float* e_out = out + (size_t)N * D;        // N
    unsigned short* g_buf = (unsigned short*)d_ws;  // N*D bf16 pre-scaled rows (4 MB)

    gate_kernel<<<(N + 15) / 16, 256, 0, stream>>>(h, W1, b1, W2, b2, e_out, g_buf, N);
    agg_kernel<<<(N + 3) / 4, 256, 0, stream>>>(A, g_buf, h_out, N);
}

// Round 2
// 381.993 us; speedup vs baseline: 1.0566x; 1.0152x over previous
//
#include <hip/hip_runtime.h>
#include <math.h>

// Problem: N=8192 nodes, D=256 features, H=64 hidden.
// out = [h_out (N*D floats), e (N floats)] concatenated, fp32.
// d_ws holds g[j,:] = bf16(e[j] * h[j,:])  (N*D bf16 = 4 MB) — fits per-XCD L2.

typedef float nfloat4 __attribute__((ext_vector_type(4)));

__device__ inline float bf16_to_f32(unsigned short s) {
    union { unsigned u; float f; } c; c.u = ((unsigned)s) << 16; return c.f;
}
__device__ inline unsigned short f32_to_bf16(float f) {   // RNE, finite inputs
    union { float f; unsigned u; } c; c.f = f;
    unsigned r = c.u + 0x7FFFu + ((c.u >> 16) & 1u);
    return (unsigned short)(r >> 16);
}
// broadcast lane l's value to all lanes (l is compile-time after unroll)
__device__ inline float rdlane(float v, int l) {
    return __builtin_bit_cast(float,
        __builtin_amdgcn_readlane(__builtin_bit_cast(int, v), l));
}

// ---------------- Kernel 1: gate + bf16 pre-scale ----------------------------
// e = sigmoid(relu(h@W1+b1)@W2+b2); g[i,:] = bf16(e[i]*h[i,:])
// Block = 256 threads (4 waves); W1 staged TRANSPOSED in LDS: W1t[k][d],
// leading dim padded to 260 floats (1040 B = 65*16 -> float4-aligned rows,
// b128 reads spread across banks: lanes 0..7 cover all 32 banks).
// Lane k reads its 4 weights per step as ONE ds_read_b128 (64 LDS instrs/row
// instead of 256 b32). FMA order identical to v2 -> bit-identical e.
__global__ __launch_bounds__(256) void gate_kernel(const float* __restrict__ h,
                                                   const float* __restrict__ W1,
                                                   const float* __restrict__ b1,
                                                   const float* __restrict__ W2,
                                                   const float* __restrict__ b2,
                                                   float* __restrict__ e_out,
                                                   unsigned short* __restrict__ g_out,
                                                   int N) {
    __shared__ float W1t[64][260];             // 66.5 KB -> still 2 blocks/CU
    const int tid = threadIdx.x;

    // stage transposed: thread t copies elements idx = t + 256*it
    // (coalesced global dword reads; scattered b32 LDS writes, ~8-way, once)
    #pragma unroll
    for (int it = 0; it < 64; ++it) {
        const int idx = tid + 256 * it;        // < 16384
        W1t[idx & 63][idx >> 6] = W1[idx];
    }
    __syncthreads();

    const int wave = tid >> 6;
    const int k    = tid & 63;
    const float b1k = b1[k];
    const float w2k = W2[k];
    const float b2v = b2[0];

    const int base = blockIdx.x * 16;
    for (int r = wave; r < 16; r += 4) {
        const int i = base + r;
        if (i >= N) break;
        const float4* hv = reinterpret_cast<const float4*>(h + (size_t)i * 256);
        float4 hr = hv[k];                     // one coalesced 1 KB row load
        float acc = 0.f;
        #pragma unroll
        for (int d4 = 0; d4 < 64; ++d4) {
            // lane d4 holds h[i, 4*d4 .. 4*d4+3]
            float ax = rdlane(hr.x, d4);
            float ay = rdlane(hr.y, d4);
            float az = rdlane(hr.z, d4);
            float aw = rdlane(hr.w, d4);
            const float4 w = *reinterpret_cast<const float4*>(&W1t[k][4 * d4]);
            acc = fmaf(ax, w.x, acc);
            acc = fmaf(ay, w.y, acc);
            acc = fmaf(az, w.z, acc);
            acc = fmaf(aw, w.w, acc);
        }
        float v = fmaxf(acc + b1k, 0.f) * w2k;
        #pragma unroll
        for (int off = 32; off > 0; off >>= 1) v += __shfl_down(v, off);
        float vs = __shfl(v, 0);
        float ev = 1.f / (1.f + expf(-(vs + b2v)));
        if (k == 0) e_out[i] = ev;
        // g[i, 4k..4k+3] = bf16(ev * h[i, 4k..4k+3])  (8 B/lane store)
        ushort4 p;
        p.x = f32_to_bf16(ev * hr.x);
        p.y = f32_to_bf16(ev * hr.y);
        p.z = f32_to_bf16(ev * hr.z);
        p.w = f32_to_bf16(ev * hr.w);
        reinterpret_cast<ushort4*>(g_out + (size_t)i * 256)[k] = p;
    }
}

// ---------------- Kernel 2: h_out[i,:] = sum_{j: A[i,j]>0} g[j,:] ------------
// One wave per row; lane owns features 4*lane..4*lane+3 (fp32 float4 acc).
// A scanned with NON-TEMPORAL float4 loads (zero reuse, evict-first -> doesn't
// displace the 4 MB bf16 g from L2).
// v3 ordering fix: vmcnt retires in issue order, so in v2 the gather-consume
// waits drained the A-prefetch issued just before them (stream duty cycle
// loss). Now: ballot -> issue FIRST gather batch -> issue A-prefetch ->
// consume gathers (wait = vmcnt(1), prefetch stays in flight). Only rare
// multi-edge sub-masks (while loop) still entangle with the prefetch.
__global__ __launch_bounds__(256) void agg_kernel(const float* __restrict__ A,
                                                  const unsigned short* __restrict__ g,
                                                  float* __restrict__ h_out,
                                                  int N) {
    const int tid  = threadIdx.x;
    const int lane = tid & 63;
    const int i    = blockIdx.x * 4 + (tid >> 6);   // row per wave
    if (i >= N) return;

    const nfloat4* Arow = reinterpret_cast<const nfloat4*>(A + (size_t)i * N);
    const ushort4* gv   = reinterpret_cast<const ushort4*>(g);  // g[j][4d..] = gv[j*64+d]

    float4 acc = {0.f, 0.f, 0.f, 0.f};
    const int groups = N / 256;                     // 32

    nfloat4 a0 = __builtin_nontemporal_load(&Arow[lane]);        // group 0
    nfloat4 a1 = __builtin_nontemporal_load(&Arow[64 + lane]);   // group 1
    nfloat4 a2 = {0.f, 0.f, 0.f, 0.f};

    for (int gi = 0; gi < groups; ++gi) {
        unsigned long long mx = __ballot(a0.x > 0.f);
        unsigned long long my = __ballot(a0.y > 0.f);
        unsigned long long mz = __ballot(a0.z > 0.f);
        unsigned long long mw = __ballot(a0.w > 0.f);
        const int jb = gi * 256;

        // ---- first gather batch: issued BEFORE the prefetch ----
        ushort4 ux, uy, uz, uw;
        bool px = mx != 0, py = my != 0, pz = mz != 0, pw = mw != 0;
        if (px) { int b = __builtin_ctzll(mx); mx &= mx - 1;
                  ux = gv[(size_t)(jb + 4 * b + 0) * 64 + lane]; }
        if (py) { int b = __builtin_ctzll(my); my &= my - 1;
                  uy = gv[(size_t)(jb + 4 * b + 1) * 64 + lane]; }
        if (pz) { int b = __builtin_ctzll(mz); mz &= mz - 1;
                  uz = gv[(size_t)(jb + 4 * b + 2) * 64 + lane]; }
        if (pw) { int b = __builtin_ctzll(mw); mw &= mw - 1;
                  uw = gv[(size_t)(jb + 4 * b + 3) * 64 + lane]; }

        // ---- A-prefetch issued after the gathers: consuming the gathers
        //      waits vmcnt(1) and leaves this load in flight ----
        if (gi + 2 < groups)
            a2 = __builtin_nontemporal_load(&Arow[(gi + 2) * 64 + lane]);

        if (px) { acc.x += bf16_to_f32(ux.x); acc.y += bf16_to_f32(ux.y);
                  acc.z += bf16_to_f32(ux.z); acc.w += bf16_to_f32(ux.w); }
        if (py) { acc.x += bf16_to_f32(uy.x); acc.y += bf16_to_f32(uy.y);
                  acc.z += bf16_to_f32(uy.z); acc.w += bf16_to_f32(uy.w); }
        if (pz) { acc.x += bf16_to_f32(uz.x); acc.y += bf16_to_f32(uz.y);
                  acc.z += bf16_to_f32(uz.z); acc.w += bf16_to_f32(uz.w); }
        if (pw) { acc.x += bf16_to_f32(uw.x); acc.y += bf16_to_f32(uw.y);
                  acc.z += bf16_to_f32(uw.z); acc.w += bf16_to_f32(uw.w); }

        // ---- remaining (rare) rounds ----
        while (mx | my | mz | mw) {
            px = mx != 0; py = my != 0; pz = mz != 0; pw = mw != 0;
            if (px) { int b = __builtin_ctzll(mx); mx &= mx - 1;
                      ux = gv[(size_t)(jb + 4 * b + 0) * 64 + lane]; }
            if (py) { int b = __builtin_ctzll(my); my &= my - 1;
                      uy = gv[(size_t)(jb + 4 * b + 1) * 64 + lane]; }
            if (pz) { int b = __builtin_ctzll(mz); mz &= mz - 1;
                      uz = gv[(size_t)(jb + 4 * b + 2) * 64 + lane]; }
            if (pw) { int b = __builtin_ctzll(mw); mw &= mw - 1;
                      uw = gv[(size_t)(jb + 4 * b + 3) * 64 + lane]; }
            if (px) { acc.x += bf16_to_f32(ux.x); acc.y += bf16_to_f32(ux.y);
                      acc.z += bf16_to_f32(ux.z); acc.w += bf16_to_f32(ux.w); }
            if (py) { acc.x += bf16_to_f32(uy.x); acc.y += bf16_to_f32(uy.y);
                      acc.z += bf16_to_f32(uy.z); acc.w += bf16_to_f32(uy.w); }
            if (pz) { acc.x += bf16_to_f32(uz.x); acc.y += bf16_to_f32(uz.y);
                      acc.z += bf16_to_f32(uz.z); acc.w += bf16_to_f32(uz.w); }
            if (pw) { acc.x += bf16_to_f32(uw.x); acc.y += bf16_to_f32(uw.y);
                      acc.z += bf16_to_f32(uw.z); acc.w += bf16_to_f32(uw.w); }
        }
        a0 = a1; a1 = a2;
    }

    // write-once output: non-temporal, keep L2 for g
    nfloat4 r; r.x = acc.x; r.y = acc.y; r.z = acc.z; r.w = acc.w;
    nfloat4* outv = reinterpret_cast<nfloat4*>(h_out + (size_t)i * 256);
    __builtin_nontemporal_store(r, &outv[lane]);
}

extern "C" void kernel_launch(void* const* d_in, const int* in_sizes, int n_in,
                              void* d_out, int out_size, void* d_ws, size_t ws_size,
                              hipStream_t stream) {
    const float* A  = (const float*)d_in[0];   // [N, N]
    const float* h  = (const float*)d_in[1];   // [N, D]
    const float* W1 = (const float*)d_in[2];   // [D, H]
    const float* b1 = (const float*)d_in[3];   // [H]
    const float* W2 = (const float*)d_in[4];   // [H, 1]
    const float* b2 = (const float*)d_in[5];   // [1]

    const int H = in_sizes[3];                 // 64
    const int D = in_sizes[2] / H;             // 256
    const int N = in_sizes[1] / D;             // 8192

    float* out   = (float*)d_out;
    float* h_out = out;                        // N*D
    float* e_out = out + (size_t)N * D;        // N
    unsigned short* g_buf = (unsigned short*)d_ws;  // N*D bf16 pre-scaled rows (4 MB)

    gate_kernel<<<(N + 15) / 16, 256, 0, stream>>>(h, W1, b1, W2, b2, e_out, g_buf, N);
    agg_kernel<<<(N + 3) / 4, 256, 0, stream>>>(A, g_buf, h_out, N);
}